// Round 10
// baseline (6554.611 us; speedup 1.0000x reference)
//
#include <hip/hip_runtime.h>

#define DI __device__ __forceinline__

// ---------------- workspace layout (4-byte element offsets) ----------------
enum : int {
  OFF_XYZF = 0,                          // [4][8192][3] f32 (z = pipe*2+b)
  OFF_FEAF = OFF_XYZF + 4*8192*3,        // [4][8192][10]
  OFF_NX1  = OFF_FEAF + 4*8192*10,       // [4][4096][3]
  OFF_L1F  = OFF_NX1  + 4*4096*3,        // [4][4096][32]
  OFF_NX2  = OFF_L1F  + 4*4096*32,       // [4][1024][3]
  OFF_L2F  = OFF_NX2  + 4*1024*3,        // [4][1024][64]
  OFF_UH2  = OFF_L2F  + 4*1024*64,       // [4][4096][32]
  OFF_L1N  = OFF_UH2  + 4*4096*32,       // [4][4096][32]
  OFF_H3   = OFF_L1N  + 4*4096*32,       // [4][8192][32]
  OFF_L0N  = OFF_H3   + 4*8192*32,       // [4][8192][32]
  OFF_STATS= OFF_L0N  + 4*8192*32,       // 2048 f32 (2 pipes x 1024)
  OFF_GIDX1= OFF_STATS + 2048,           // [4][4096][16] int
  OFF_GIDX2= OFF_GIDX1 + 4*4096*16,      // [4][1024][16]
  OFF_UIDX = OFF_GIDX2 + 4*1024*16,      // [4][4096][8]
  WS_END   = OFF_UIDX + 4*4096*8
};
enum : int { ST_SA1A=0, ST_SA1B=64, ST_SA2A=128, ST_SA2B=192, ST_U1=320, ST_U2=384, ST_FP=448, ST_BN1=512 };

// XLA-style contracted squared-norm and dot (fma chains, ascending c)
DI float nrm3(float x, float y, float z){ return fmaf(z,z, fmaf(y,y, x*x)); }
DI float dot3(float ax,float ay,float az,float bx,float by,float bz){
  return fmaf(az,bz, fmaf(ay,by, ax*bx));
}

// DPP-based 64-lane max of a (hi,lo) u64 key; result valid in lane 63.
#define DPP_STEP(ctrl)                                                        \
  {                                                                           \
    unsigned nh = (unsigned)__builtin_amdgcn_update_dpp((int)hi,(int)hi,ctrl,0xf,0xf,false); \
    unsigned nl = (unsigned)__builtin_amdgcn_update_dpp((int)lo,(int)lo,ctrl,0xf,0xf,false); \
    bool gt = (nh>hi) | ((nh==hi) & (nl>lo));                                 \
    hi = gt?nh:hi; lo = gt?nl:lo;                                             \
  }

// ---------------- block stats reduce: sum & sumsq per channel ----------------
template<int CH>
DI void stats_accum(float* h, float* dst, float (*sred)[128])
{
  float sq[CH];
  #pragma unroll
  for (int c=0;c<CH;c++) sq[c]=h[c]*h[c];
  #pragma unroll
  for (int m=1;m<64;m<<=1){
    #pragma unroll
    for (int c=0;c<CH;c++){ h[c] += __shfl_xor(h[c], m, 64); sq[c] += __shfl_xor(sq[c], m, 64); }
  }
  const int tid=threadIdx.x, wid=tid>>6, lane=tid&63;
  if (lane==0){
    #pragma unroll
    for (int c=0;c<CH;c++){ sred[wid][c]=h[c]; sred[wid][CH+c]=sq[c]; }
  }
  __syncthreads();
  if (tid < 2*CH){
    float v = sred[0][tid]+sred[1][tid]+sred[2][tid]+sred[3][tid];
    atomicAdd(dst+tid, v);
  }
}

// ---------------- prep: gather both pipes into one z-indexed layout ----------------
__global__ __launch_bounds__(256) void prep(const float* __restrict__ p1,const float* __restrict__ f1,
                                            const float* __restrict__ p2,const float* __restrict__ f2,
                                            float* __restrict__ xyzf, float* __restrict__ feaf)
{
  const int i = blockIdx.x*256+threadIdx.x;          // 0..32767 = (z,n)
  const int z = i>>13, n = i&8191, pipe=z>>1, b=z&1;
  const float* ps = (pipe?p2:p1) + (b*8192+n)*3;
  const float* fs = (pipe?f2:f1) + (b*8192+n)*10;
  float* xo = xyzf + (z*8192+n)*3;
  float* fo = feaf + (z*8192+n)*10;
  #pragma unroll
  for (int c=0;c<3;c++)  xo[c]=ps[c];
  #pragma unroll
  for (int c=0;c<10;c++) fo[c]=fs[c];
}

// ---------------- farthest point sampling (serial argmax chain) ----------------
// Issue-bound on 1 CU -> packed-f32 scan:
//   state held as float2 ext-vectors; sub/mul/fma emit v_pk_*_f32 (full-rate
//   2-wide, IEEE-identical per lane); min/max scalarize (no pk f32 min/max).
//   LDS xyz cache packed float4 -> centroid fetch is one ds_read_b128.
//   reduce: DPP max chain -> lane63; one ds_max_u64 atomic per wave into a
//   rotating 3-deep accumulator (race-free across the single barrier);
//   all lanes broadcast-read the final key.
// Packed key (distbits<<32 | N-1-j) -> exact global first-occurrence argmax.
// Distance math bit-identical to XLA f32 fma chain (exact fminf/fmaxf).
template<int N,int NPOINT,int T>
__global__ __launch_bounds__(T) void fps_kernel(const float* __restrict__ src, float* __restrict__ dst)
{
  constexpr int P = N/T;
  constexpr int H = P/2;
  typedef float f2 __attribute__((ext_vector_type(2)));
  const int z = blockIdx.x;
  const float* xyz = src + z*N*3;
  float* nx = dst + z*NPOINT*3;
  const int t = threadIdx.x;
  __shared__ float4 sp[N];
  __shared__ unsigned long long s_acc[3];
  f2 px[H],py[H],pz[H],dist[H];
  #pragma unroll
  for (int k=0;k<P;k++){
    const int j = t + k*T;
    float x=xyz[j*3+0], y=xyz[j*3+1], w=xyz[j*3+2];
    px[k>>1][k&1]=x; py[k>>1][k&1]=y; pz[k>>1][k&1]=w;
    dist[k>>1][k&1]=1e10f;
    sp[j]=make_float4(x,y,w,0.f);
  }
  if (t==0){ s_acc[0]=0ull; s_acc[1]=0ull; s_acc[2]=0ull; }
  __syncthreads();
  unsigned long long win = (unsigned long long)(unsigned)(N-1);  // index 0
  for (int s=0;;s++){
    const int cur = (N-1) - (int)(unsigned)(win & 0xffffffffull);
    const float4 c = sp[cur];                       // one ds_read_b128
    if (t==0){ nx[s*3+0]=c.x; nx[s*3+1]=c.y; nx[s*3+2]=c.z; }
    if (s == NPOINT-1) break;
    // ---- scan: packed f32 ----
    f2 lm2 = {-1.f,-1.f};
    #pragma unroll
    for (int k=0;k<H;k++){
      f2 dx = px[k]-c.x, dy = py[k]-c.y, dz = pz[k]-c.z;   // v_pk_add (neg)
      f2 d  = __builtin_elementwise_fma(dz,dz,
              __builtin_elementwise_fma(dy,dy, dx*dx));    // v_pk_mul + 2x v_pk_fma
      f2 nd = __builtin_elementwise_min(dist[k], d);       // scalarized exact min
      dist[k]=nd;
      lm2 = __builtin_elementwise_max(lm2, nd);            // scalarized exact max
    }
    float lm = fmaxf(lm2.x, lm2.y);
    // ---- local first-occurrence index (smallest k -> smallest j for this t) ----
    int kb = 0;
    #pragma unroll
    for (int k=P-1;k>=0;k--) if (dist[k>>1][k&1]==lm) kb = k;
    unsigned hi = __float_as_uint(lm);
    unsigned lo = (unsigned)(N-1-(t+kb*T));
    // ---- in-wave: DPP max chain -> lane63 ----
    DPP_STEP(0x111)  // row_shr:1
    DPP_STEP(0x112)  // row_shr:2
    DPP_STEP(0x114)  // row_shr:4
    DPP_STEP(0x118)  // row_shr:8
    DPP_STEP(0x142)  // row_bcast15
    DPP_STEP(0x143)  // row_bcast31
    if ((t&63)==63)
      atomicMax(&s_acc[s%3], ((unsigned long long)hi<<32)|(unsigned long long)lo);
    if (t==0) s_acc[(s+1)%3] = 0ull;   // reset next-next buffer (2 barriers from its reads)
    __syncthreads();
    win = s_acc[s%3];                  // broadcast read
  }
}

// ---------------- ball query: first K in-radius indices (ascending) + argmin fallback ----
template<int NSRC,int SQ,int K>
__global__ __launch_bounds__(64) void ball_query(const float* __restrict__ qxyz, const float* __restrict__ sxyz,
                                                 int* __restrict__ gidx, float r2)
{
  __shared__ float4 tile[1024];
  const int z = blockIdx.y, tid = threadIdx.x;
  const int s = blockIdx.x*64 + tid;
  const float* q = qxyz + (z*SQ+s)*3;
  const float qx=q[0],qy=q[1],qz=q[2];
  const float qq=nrm3(qx,qy,qz);
  int cnt=0, first=0, amin=0; float dmin=3.0e38f;
  int* out = gidx + (z*SQ+s)*K;
  for (int t0=0;t0<NSRC;t0+=1024){
    __syncthreads();
    for (int i=tid;i<1024;i+=64){
      const float* p = sxyz + (z*NSRC+t0+i)*3;
      float x=p[0],y=p[1],w=p[2];
      tile[i]=make_float4(x,y,w,nrm3(x,y,w));
    }
    __syncthreads();
    for (int jj=0;jj<1024;jj++){
      float4 p = tile[jj];
      float dot=dot3(qx,qy,qz,p.x,p.y,p.z);
      float d=(qq+p.w)-2.0f*dot;
      const int j = t0+jj;
      if (d < dmin){ dmin=d; amin=j; }
      if (d <= r2 && cnt < K){ if(cnt==0) first=j; out[cnt]=j; cnt++; }
    }
  }
  const int fill = (cnt==0)? amin : first;
  for (int c=cnt;c<K;c++) out[c]=fill;
}

// ---------------- set-abstraction conv passes ----------------
template<int S,int K,int CF,int C1,int C2,int NSRC,int PASS>
__global__ __launch_bounds__(256) void sa_pass(
    const float* __restrict__ srcxyz, const float* __restrict__ srcfea,
    const float* __restrict__ qxyz, const int* __restrict__ gidx,
    const float* __restrict__ w0, const float* __restrict__ g0, const float* __restrict__ b0,
    const float* __restrict__ w1, const float* __restrict__ g1v, const float* __restrict__ b1v,
    float* __restrict__ stats, int offA, int offB, float cnt0, float cnt1,
    float* __restrict__ outp)
{
  constexpr int CIN = 3+CF;
  __shared__ float w0l[C1*CIN];
  __shared__ float w1l[PASS>=2 ? C2*C1 : 1];
  __shared__ float sc0[C1], bi0[C1];
  __shared__ float sc1[C2], bi1[C2];
  __shared__ float sred[4][128];
  const int z = blockIdx.y, pipe = z>>1, tid = threadIdx.x;
  float* stA = stats + pipe*1024 + offA;
  float* stB = stats + pipe*1024 + offB;
  for (int i=tid;i<C1*CIN;i+=256) w0l[i]=w0[i];
  if (PASS>=2){
    for (int i=tid;i<C2*C1;i+=256) w1l[i]=w1[i];
    if (tid<C1){
      float m = stA[tid]/cnt0;
      float var = stA[C1+tid]/cnt0 - m*m;
      float rs = 1.0f/sqrtf(var+1e-5f);
      float sc = rs*g0[tid];
      sc0[tid]=sc; bi0[tid]=b0[tid]-m*sc;
    }
  }
  if (PASS==3 && tid<C2){
    float m = stB[tid]/cnt1;
    float var = stB[C2+tid]/cnt1 - m*m;
    float rs = 1.0f/sqrtf(var+1e-5f);
    float sc = rs*g1v[tid];
    sc1[tid]=sc; bi1[tid]=b1v[tid]-m*sc;
  }
  __syncthreads();
  const int item = blockIdx.x*256+tid;
  const int s = item/K;
  const int j = gidx[(z*S+s)*K + (item%K)];
  const float* q = qxyz + (z*S+s)*3;
  const float* p = srcxyz + (z*NSRC+j)*3;
  float f[CIN];
  f[0]=p[0]-q[0]; f[1]=p[1]-q[1]; f[2]=p[2]-q[2];
  const float* fe = srcfea + (z*NSRC+j)*CF;
  #pragma unroll
  for (int c=0;c<CF;c++) f[3+c]=fe[c];
  float h1[C1];
  #pragma unroll
  for (int o=0;o<C1;o++){
    float a=0.f;
    #pragma unroll
    for (int c=0;c<CIN;c++) a = fmaf(w0l[o*CIN+c], f[c], a);
    h1[o]=a;
  }
  if (PASS==1){ stats_accum<C1>(h1, stA, sred); return; }
  float f2v[C1];
  #pragma unroll
  for (int o=0;o<C1;o++) f2v[o]=fmaxf(fmaf(h1[o],sc0[o],bi0[o]), 0.f);
  float h2[C2];
  #pragma unroll
  for (int o=0;o<C2;o++){
    float a=0.f;
    #pragma unroll
    for (int c=0;c<C1;c++) a = fmaf(w1l[o*C1+c], f2v[c], a);
    h2[o]=a;
  }
  if (PASS==2){ stats_accum<C2>(h2, stB, sred); return; }
  #pragma unroll
  for (int o=0;o<C2;o++) h2[o]=fmaxf(fmaf(h2[o],sc1[o],bi1[o]), 0.f);
  #pragma unroll
  for (int msk=1; msk<K; msk<<=1){
    #pragma unroll
    for (int o=0;o<C2;o++) h2[o]=fmaxf(h2[o], __shfl_xor(h2[o], msk, 64));
  }
  if ((tid & (K-1))==0){
    float* op = outp + (z*S+s)*C2;
    #pragma unroll
    for (int o=0;o<C2;o++) op[o]=h2[o];
  }
}

// ---------------- upconv: stable 8-NN (64-thread blocks, order-preserving) ----------------
__global__ __launch_bounds__(64) void up_top8(const float* __restrict__ nx1, const float* __restrict__ nx2,
                                              int* __restrict__ uidx)
{
  __shared__ float4 tile[1024];
  const int z=blockIdx.y, tid=threadIdx.x;
  const int s=blockIdx.x*64+tid;
  const float* q = nx1 + (z*4096+s)*3;
  const float qx=q[0],qy=q[1],qz=q[2];
  const float qq=nrm3(qx,qy,qz);
  for (int i=tid;i<1024;i+=64){
    const float* p = nx2 + (z*1024+i)*3;
    float x=p[0],y=p[1],w=p[2];
    tile[i]=make_float4(x,y,w,nrm3(x,y,w));
  }
  __syncthreads();
  float d[8]; int id[8];
  #pragma unroll
  for (int r=0;r<8;r++){ d[r]=3e38f; id[r]=0; }
  for (int j=0;j<1024;j++){
    float4 p=tile[j];
    float dt=dot3(qx,qy,qz,p.x,p.y,p.z);
    float dd=(qq+p.w)-2.0f*dt;
    if (dd<d[7]){
      d[7]=dd; id[7]=j;
      #pragma unroll
      for (int r=7;r>0;r--){
        if (d[r]<d[r-1]){ float td=d[r-1]; d[r-1]=d[r]; d[r]=td; int ti=id[r-1]; id[r-1]=id[r]; id[r]=ti; }
      }
    }
  }
  int* o = uidx + (z*4096+s)*8;
  #pragma unroll
  for (int r=0;r<8;r++) o[r]=id[r];
}

template<int PASS>
__global__ __launch_bounds__(256) void up_pass(
    const float* __restrict__ nx1, const float* __restrict__ nx2,
    const float* __restrict__ l2f, const float* __restrict__ l1f,
    const int* __restrict__ uidx,
    const float* __restrict__ w1, const float* __restrict__ g1v, const float* __restrict__ b1v,
    const float* __restrict__ w2,
    float* __restrict__ stats, float* __restrict__ uh2)
{
  __shared__ float w1l[32*67];
  __shared__ float w2l[PASS==2?32*64:1];
  __shared__ float sc0[32], bi0[32];
  __shared__ float sred[4][128];
  const int z=blockIdx.y, pipe=z>>1, tid=threadIdx.x;
  float* stU1 = stats + pipe*1024 + ST_U1;
  float* stU2 = stats + pipe*1024 + ST_U2;
  for (int i=tid;i<32*67;i+=256) w1l[i]=w1[i];
  if (PASS==2){
    for (int i=tid;i<32*64;i+=256) w2l[i]=w2[i];
    if (tid<32){
      float m=stU1[tid]/65536.f;
      float var=stU1[32+tid]/65536.f - m*m;
      float rs=1.0f/sqrtf(var+1e-5f);
      float sc=rs*g1v[tid];
      sc0[tid]=sc; bi0[tid]=b1v[tid]-m*sc;
    }
  }
  __syncthreads();
  const int item = blockIdx.x*256+tid;
  const int s = item>>3, k = item&7;
  const int j = uidx[(z*4096+s)*8+k];
  float f67[67];
  const float* fe = l2f + (z*1024+j)*64;
  #pragma unroll
  for (int c=0;c<64;c++) f67[c]=fe[c];
  const float* pp = nx2 + (z*1024+j)*3;
  const float* qv = nx1 + (z*4096+s)*3;
  f67[64]=pp[0]-qv[0]; f67[65]=pp[1]-qv[1]; f67[66]=pp[2]-qv[2];
  float h[32];
  #pragma unroll
  for (int o=0;o<32;o++){
    float a=0.f;
    #pragma unroll
    for (int c=0;c<67;c++) a=fmaf(w1l[o*67+c], f67[c], a);
    h[o]=a;
  }
  if (PASS==1){ stats_accum<32>(h, stU1, sred); return; }
  #pragma unroll
  for (int o=0;o<32;o++) h[o]=fmaxf(fmaf(h[o],sc0[o],bi0[o]),0.f);
  #pragma unroll
  for (int msk=1; msk<8; msk<<=1){
    #pragma unroll
    for (int o=0;o<32;o++) h[o]=fmaxf(h[o], __shfl_xor(h[o],msk,64));
  }
  float h2[32];
  if (k==0){
    const float* l1 = l1f + (z*4096+s)*32;
    #pragma unroll
    for (int o=0;o<32;o++){
      float a=0.f;
      #pragma unroll
      for (int c=0;c<32;c++) a=fmaf(w2l[o*64+c], h[c], a);
      #pragma unroll
      for (int c=0;c<32;c++) a=fmaf(w2l[o*64+32+c], l1[c], a);
      h2[o]=a;
    }
    float* up = uh2 + (z*4096+s)*32;
    #pragma unroll
    for (int o=0;o<32;o++) up[o]=h2[o];
  } else {
    #pragma unroll
    for (int o=0;o<32;o++) h2[o]=0.f;
  }
  stats_accum<32>(h2, stU2, sred);
}

__global__ __launch_bounds__(256) void up_norm(const float* __restrict__ uh2, const float* __restrict__ g,
                                               const float* __restrict__ b, const float* __restrict__ stats,
                                               float* __restrict__ l1n)
{
  const int i = blockIdx.x*256+threadIdx.x;   // < 4*4096*32
  const int z = i>>17, pipe = z>>1, c = i&31;
  const float* st = stats + pipe*1024 + ST_U2;
  float m = st[c]/8192.f;
  float var = st[32+c]/8192.f - m*m;
  float rs = 1.0f/sqrtf(var+1e-5f);
  float sc = rs*g[c];
  float bi = b[c]-m*sc;
  l1n[i]=fmaxf(fmaf(uh2[i],sc,bi),0.f);
}

// ---------------- feature propagation: 3-NN interpolate + conv ----------------
__global__ __launch_bounds__(256) void fp_kern(
  const float* __restrict__ xyzf, const float* __restrict__ feaf,
  const float* __restrict__ nx1, const float* __restrict__ l1n,
  const float* __restrict__ fpw, float* __restrict__ stats, float* __restrict__ h3)
{
  __shared__ float4 tile[2048];
  __shared__ float wl[32*42];
  __shared__ float sred[4][128];
  const int z=blockIdx.y, pipe=z>>1, tid=threadIdx.x;
  for (int i=tid;i<32*42;i+=256) wl[i]=fpw[i];
  const int n = blockIdx.x*256+tid;
  const float* q = xyzf + (z*8192+n)*3;
  const float qx=q[0],qy=q[1],qz=q[2];
  const float qq2=nrm3(qx,qy,qz);
  float d0=3e38f,d1=3e38f,d2=3e38f; int i0=0,i1=0,i2=0;
  for (int t0=0;t0<4096;t0+=2048){
    __syncthreads();
    for (int i=tid;i<2048;i+=256){
      const float* p = nx1 + (z*4096+t0+i)*3;
      float x=p[0],y=p[1],w=p[2];
      tile[i]=make_float4(x,y,w,nrm3(x,y,w));
    }
    __syncthreads();
    for (int jj=0;jj<2048;jj++){
      float4 p=tile[jj];
      float dt=dot3(qx,qy,qz,p.x,p.y,p.z);
      float d=(qq2+p.w)-2.0f*dt;
      if (d<d2){
        d2=d; i2=t0+jj;
        if (d2<d1){ float td=d1; d1=d2; d2=td; int ti=i1; i1=i2; i2=ti; }
        if (d1<d0){ float td=d0; d0=d1; d1=td; int ti=i0; i0=i1; i1=ti; }
      }
    }
  }
  d0=fmaxf(d0,1e-10f); d1=fmaxf(d1,1e-10f); d2=fmaxf(d2,1e-10f);
  float w0=1.0f/d0, w1=1.0f/d1, w2=1.0f/d2;
  float wsum=(w0+w1)+w2;
  w0/=wsum; w1/=wsum; w2/=wsum;
  const float* A = l1n + (z*4096+i0)*32;
  const float* B = l1n + (z*4096+i1)*32;
  const float* C = l1n + (z*4096+i2)*32;
  float f[42];
  #pragma unroll
  for (int c=0;c<32;c++) f[c]=fmaf(C[c],w2, fmaf(B[c],w1, A[c]*w0));
  const float* fe = feaf + (z*8192+n)*10;
  #pragma unroll
  for (int c=0;c<10;c++) f[32+c]=fe[c];
  float h[32];
  #pragma unroll
  for (int o=0;o<32;o++){
    float a=0.f;
    #pragma unroll
    for (int c=0;c<42;c++) a=fmaf(wl[o*42+c], f[c], a);
    h[o]=a;
    h3[(z*8192+n)*32+o]=a;
  }
  stats_accum<32>(h, stats + pipe*1024 + ST_FP, sred);
}

__global__ __launch_bounds__(256) void fp_post(const float* __restrict__ h3, const float* __restrict__ g,
                                               const float* __restrict__ b, float* __restrict__ stats,
                                               float* __restrict__ l0n)
{
  __shared__ float sc[32], bi[32];
  __shared__ float sred[4][128];
  const int tid=threadIdx.x;
  const int row = blockIdx.x*256+tid;     // 32768
  const int pipe = row>>14;
  float* stF = stats + pipe*1024 + ST_FP;
  float* stB = stats + pipe*1024 + ST_BN1;
  if (tid<32){
    float m=stF[tid]/16384.f;
    float var=stF[32+tid]/16384.f-m*m;
    float rs=1.0f/sqrtf(var+1e-5f);
    float s=rs*g[tid];
    sc[tid]=s; bi[tid]=b[tid]-m*s;
  }
  __syncthreads();
  float x[32];
  #pragma unroll
  for (int c=0;c<32;c++){ x[c]=fmaxf(fmaf(h3[row*32+c],sc[c],bi[c]),0.f); l0n[row*32+c]=x[c]; }
  stats_accum<32>(x, stB, sred);
}

__global__ __launch_bounds__(256) void final_kern(
  const float* __restrict__ l0n, const float* __restrict__ g, const float* __restrict__ b,
  const float* __restrict__ cw, const float* __restrict__ cb,
  const float* __restrict__ p1, const float* __restrict__ p2,
  const float* __restrict__ stats, float* __restrict__ out)
{
  __shared__ float sc[32], bi[32], wl[512], bl[16];
  const int tid=threadIdx.x;
  const int row = blockIdx.x*256+tid;
  const int z=row>>13, pipe=z>>1, bb=z&1, n=row&8191;
  const float* st = stats + pipe*1024 + ST_BN1;
  if (tid<32){
    float m=st[tid]/16384.f;
    float var=st[32+tid]/16384.f-m*m;
    float rs=1.0f/sqrtf(var+1e-5f);
    float s=rs*g[tid];
    sc[tid]=s; bi[tid]=b[tid]-m*s;
  }
  for (int i=tid;i<512;i+=256) wl[i]=cw[i];
  if (tid<16) bl[tid]=cb[tid];
  __syncthreads();
  float x[32];
  #pragma unroll
  for (int c=0;c<32;c++) x[c]=fmaxf(fmaf(l0n[row*32+c],sc[c],bi[c]),0.f);
  float* o = out + row*19;
  const float* ps = (pipe?p2:p1) + (bb*8192+n)*3;
  o[0]=ps[0]; o[1]=ps[1]; o[2]=ps[2];
  #pragma unroll
  for (int oo=0;oo<16;oo++){
    float a=0.f;
    #pragma unroll
    for (int c=0;c<32;c++) a=fmaf(wl[oo*32+c],x[c],a);
    o[3+oo]=a+bl[oo];
  }
}

// ---------------- host ----------------
extern "C" void kernel_launch(void* const* d_in, const int* in_sizes, int n_in,
                              void* d_out, int out_size, void* d_ws, size_t ws_size,
                              hipStream_t stream)
{
  (void)in_sizes; (void)n_in; (void)out_size; (void)ws_size;
  const float* p1 = (const float*)d_in[0];
  const float* f1 = (const float*)d_in[1];
  const float* p2 = (const float*)d_in[2];
  const float* f2 = (const float*)d_in[3];
  const float *sa1_w0=(const float*)d_in[4], *sa1_g0=(const float*)d_in[5], *sa1_b0=(const float*)d_in[6];
  const float *sa1_w1=(const float*)d_in[7], *sa1_g1=(const float*)d_in[8], *sa1_b1=(const float*)d_in[9];
  const float *sa2_w0=(const float*)d_in[10],*sa2_g0=(const float*)d_in[11],*sa2_b0=(const float*)d_in[12];
  const float *sa2_w1=(const float*)d_in[13],*sa2_g1=(const float*)d_in[14],*sa2_b1=(const float*)d_in[15];
  const float *su1_w1=(const float*)d_in[16],*su1_g1=(const float*)d_in[17],*su1_b1=(const float*)d_in[18];
  const float *su1_w2=(const float*)d_in[19],*su1_g2=(const float*)d_in[20],*su1_b2=(const float*)d_in[21];
  const float *fp_w=(const float*)d_in[22], *fp_g=(const float*)d_in[23], *fp_b=(const float*)d_in[24];
  const float *bn1_g=(const float*)d_in[25],*bn1_b=(const float*)d_in[26];
  const float *conv2_w=(const float*)d_in[27],*conv2_b=(const float*)d_in[28];
  float* wsf=(float*)d_ws; int* wsi=(int*)d_ws;
  float* xyzf=wsf+OFF_XYZF; float* feaf=wsf+OFF_FEAF;
  float* nx1=wsf+OFF_NX1; float* l1f=wsf+OFF_L1F;
  float* nx2=wsf+OFF_NX2; float* l2f=wsf+OFF_L2F;
  float* uh2=wsf+OFF_UH2; float* l1n=wsf+OFF_L1N;
  float* h3=wsf+OFF_H3; float* l0n=wsf+OFF_L0N;
  float* stats=wsf+OFF_STATS;
  int* gidx1=wsi+OFF_GIDX1; int* gidx2=wsi+OFF_GIDX2; int* uidx=wsi+OFF_UIDX;
  // radius*radius is computed in Python f64 then demoted to f32
  const float R2A=(float)(0.1*0.1), R2B=(float)(0.2*0.2);

  hipMemsetAsync(stats, 0, 2048*sizeof(float), stream);
  prep<<<128,256,0,stream>>>(p1,f1,p2,f2,xyzf,feaf);
  fps_kernel<8192,4096,512><<<4,512,0,stream>>>(xyzf, nx1);
  ball_query<8192,4096,16><<<dim3(64,4),64,0,stream>>>(nx1, xyzf, gidx1, R2A);
  sa_pass<4096,16,10,16,32,8192,1><<<dim3(256,4),256,0,stream>>>(xyzf,feaf,nx1,gidx1,
      sa1_w0,sa1_g0,sa1_b0,sa1_w1,sa1_g1,sa1_b1, stats,ST_SA1A,ST_SA1B,131072.f,131072.f, l1f);
  sa_pass<4096,16,10,16,32,8192,2><<<dim3(256,4),256,0,stream>>>(xyzf,feaf,nx1,gidx1,
      sa1_w0,sa1_g0,sa1_b0,sa1_w1,sa1_g1,sa1_b1, stats,ST_SA1A,ST_SA1B,131072.f,131072.f, l1f);
  sa_pass<4096,16,10,16,32,8192,3><<<dim3(256,4),256,0,stream>>>(xyzf,feaf,nx1,gidx1,
      sa1_w0,sa1_g0,sa1_b0,sa1_w1,sa1_g1,sa1_b1, stats,ST_SA1A,ST_SA1B,131072.f,131072.f, l1f);
  fps_kernel<4096,1024,512><<<4,512,0,stream>>>(nx1, nx2);
  ball_query<4096,1024,16><<<dim3(16,4),64,0,stream>>>(nx2, nx1, gidx2, R2B);
  sa_pass<1024,16,32,32,64,4096,1><<<dim3(64,4),256,0,stream>>>(nx1,l1f,nx2,gidx2,
      sa2_w0,sa2_g0,sa2_b0,sa2_w1,sa2_g1,sa2_b1, stats,ST_SA2A,ST_SA2B,32768.f,32768.f, l2f);
  sa_pass<1024,16,32,32,64,4096,2><<<dim3(64,4),256,0,stream>>>(nx1,l1f,nx2,gidx2,
      sa2_w0,sa2_g0,sa2_b0,sa2_w1,sa2_g1,sa2_b1, stats,ST_SA2A,ST_SA2B,32768.f,32768.f, l2f);
  sa_pass<1024,16,32,32,64,4096,3><<<dim3(64,4),256,0,stream>>>(nx1,l1f,nx2,gidx2,
      sa2_w0,sa2_g0,sa2_b0,sa2_w1,sa2_g1,sa2_b1, stats,ST_SA2A,ST_SA2B,32768.f,32768.f, l2f);
  up_top8<<<dim3(64,4),64,0,stream>>>(nx1,nx2,uidx);
  up_pass<1><<<dim3(128,4),256,0,stream>>>(nx1,nx2,l2f,l1f,uidx,su1_w1,su1_g1,su1_b1,su1_w2,stats,uh2);
  up_pass<2><<<dim3(128,4),256,0,stream>>>(nx1,nx2,l2f,l1f,uidx,su1_w1,su1_g1,su1_b1,su1_w2,stats,uh2);
  up_norm<<<2048,256,0,stream>>>(uh2,su1_g2,su1_b2,stats,l1n);
  fp_kern<<<dim3(32,4),256,0,stream>>>(xyzf,feaf,nx1,l1n,fp_w,stats,h3);
  fp_post<<<128,256,0,stream>>>(h3,fp_g,fp_b,stats,l0n);
  final_kern<<<128,256,0,stream>>>(l0n,bn1_g,bn1_b,conv2_w,conv2_b,p1,p2,stats,(float*)d_out);
}

// Round 12
// 5811.939 us; speedup vs baseline: 1.1278x; 1.1278x over previous
//
#include <hip/hip_runtime.h>

#define DI __device__ __forceinline__

// ---------------- workspace layout (4-byte element offsets) ----------------
enum : int {
  OFF_XYZF = 0,                          // [4][8192][3] f32 (z = pipe*2+b)
  OFF_FEAF = OFF_XYZF + 4*8192*3,        // [4][8192][10]
  OFF_NX1  = OFF_FEAF + 4*8192*10,       // [4][4096][3]
  OFF_L1F  = OFF_NX1  + 4*4096*3,        // [4][4096][32]
  OFF_NX2  = OFF_L1F  + 4*4096*32,       // [4][1024][3]
  OFF_L2F  = OFF_NX2  + 4*1024*3,        // [4][1024][64]
  OFF_UH2  = OFF_L2F  + 4*1024*64,       // [4][4096][32]
  OFF_L1N  = OFF_UH2  + 4*4096*32,       // [4][4096][32]
  OFF_H3   = OFF_L1N  + 4*4096*32,       // [4][8192][32]
  OFF_L0N  = OFF_H3   + 4*8192*32,       // [4][8192][32]
  OFF_STATS= OFF_L0N  + 4*8192*32,       // 2048 f32 (2 pipes x 1024)
  OFF_GIDX1= OFF_STATS + 2048,           // [4][4096][16] int
  OFF_GIDX2= OFF_GIDX1 + 4*4096*16,      // [4][1024][16]
  OFF_UIDX = OFF_GIDX2 + 4*1024*16,      // [4][4096][8]
  WS_END   = OFF_UIDX + 4*4096*8
};
enum : int { ST_SA1A=0, ST_SA1B=64, ST_SA2A=128, ST_SA2B=192, ST_U1=320, ST_U2=384, ST_FP=448, ST_BN1=512 };

// XLA-style contracted squared-norm and dot (fma chains, ascending c)
DI float nrm3(float x, float y, float z){ return fmaf(z,z, fmaf(y,y, x*x)); }
DI float dot3(float ax,float ay,float az,float bx,float by,float bz){
  return fmaf(az,bz, fmaf(ay,by, ax*bx));
}

// ---- all-lanes 64-wide butterfly reduce via DPP + swizzle + shfl ----
// steps xor1 (quad_perm 0xB1), xor2 (quad_perm 0x4E), xor7 (row_half_mirror),
// xor15 (row_mirror), xor16 (ds_swizzle 0x401F), xor32 (shfl).
// span{1,2,7,15,16,32} == span{1,2,4,8,16,32} == full wave (15-i = 15^i).
template<int CTRL>
DI float dpp_fmax(float v){
  int o = __builtin_amdgcn_update_dpp(0, __float_as_int(v), CTRL, 0xf, 0xf, true);
  return fmaxf(v, __int_as_float(o));
}
template<int CTRL>
DI int dpp_imin(int v){
  int o = __builtin_amdgcn_update_dpp(0x7fffffff, v, CTRL, 0xf, 0xf, true);
  return v < o ? v : o;
}
DI float wave_fmax(float v){
  v = dpp_fmax<0xB1>(v);   // quad_perm [1,0,3,2]  = xor1
  v = dpp_fmax<0x4E>(v);   // quad_perm [2,3,0,1]  = xor2
  v = dpp_fmax<0x141>(v);  // row_half_mirror      = xor7
  v = dpp_fmax<0x140>(v);  // row_mirror           = xor15
  v = fmaxf(v, __int_as_float(__builtin_amdgcn_ds_swizzle(__float_as_int(v), 0x401F))); // xor16
  v = fmaxf(v, __shfl_xor(v, 32, 64));                                                  // xor32
  return v;
}
DI int wave_imin(int v){
  v = dpp_imin<0xB1>(v);
  v = dpp_imin<0x4E>(v);
  v = dpp_imin<0x141>(v);
  v = dpp_imin<0x140>(v);
  { int o = __builtin_amdgcn_ds_swizzle(v, 0x401F); v = v<o?v:o; }
  { int o = __shfl_xor(v, 32, 64);                  v = v<o?v:o; }
  return v;
}

// ---------------- block stats reduce: sum & sumsq per channel ----------------
template<int CH>
DI void stats_accum(float* h, float* dst, float (*sred)[128])
{
  float sq[CH];
  #pragma unroll
  for (int c=0;c<CH;c++) sq[c]=h[c]*h[c];
  #pragma unroll
  for (int m=1;m<64;m<<=1){
    #pragma unroll
    for (int c=0;c<CH;c++){ h[c] += __shfl_xor(h[c], m, 64); sq[c] += __shfl_xor(sq[c], m, 64); }
  }
  const int tid=threadIdx.x, wid=tid>>6, lane=tid&63;
  if (lane==0){
    #pragma unroll
    for (int c=0;c<CH;c++){ sred[wid][c]=h[c]; sred[wid][CH+c]=sq[c]; }
  }
  __syncthreads();
  if (tid < 2*CH){
    float v = sred[0][tid]+sred[1][tid]+sred[2][tid]+sred[3][tid];
    atomicAdd(dst+tid, v);
  }
}

// ---------------- prep: gather both pipes into one z-indexed layout ----------------
__global__ __launch_bounds__(256) void prep(const float* __restrict__ p1,const float* __restrict__ f1,
                                            const float* __restrict__ p2,const float* __restrict__ f2,
                                            float* __restrict__ xyzf, float* __restrict__ feaf)
{
  const int i = blockIdx.x*256+threadIdx.x;          // 0..32767 = (z,n)
  const int z = i>>13, n = i&8191, pipe=z>>1, b=z&1;
  const float* ps = (pipe?p2:p1) + (b*8192+n)*3;
  const float* fs = (pipe?f2:f1) + (b*8192+n)*10;
  float* xo = xyzf + (z*8192+n)*3;
  float* fo = feaf + (z*8192+n)*10;
  #pragma unroll
  for (int c=0;c<3;c++)  xo[c]=ps[c];
  #pragma unroll
  for (int c=0;c<10;c++) fo[c]=fs[c];
}

// ---------------- farthest point sampling (serial argmax chain) ----------------
// R9 scan (measured best: scalar f32 pair-unrolled + rescan) + cheaper reduce:
//   phase 1: all-lanes f32 max butterfly (4 DPP + swizzle + shfl, fused v_max)
//   phase 2: jc = tied ? j : INT_MAX; all-lanes u32 min butterfly -> jmin
//   cross-wave: lane0 packs (distbits<<32 | N-1-jmin) -> one ds atomic max into
//   rotating 3-deep accumulator; ONE barrier; all lanes broadcast-read key.
// Winner sequence == global first-occurrence argmax (max dist, then min j).
// Distance math bit-identical to XLA f32 fma chain (exact fminf/fmaxf).
template<int N,int NPOINT,int T>
__global__ __launch_bounds__(T) void fps_kernel(const float* __restrict__ src, float* __restrict__ dst)
{
  constexpr int P = N/T;
  const int z = blockIdx.x;
  const float* xyz = src + z*N*3;
  float* nx = dst + z*NPOINT*3;
  const int t = threadIdx.x;
  __shared__ float sx[N], sy[N], szz[N];
  __shared__ unsigned long long s_acc[3];
  float px[P],py[P],pz[P],dist[P];
  #pragma unroll
  for (int k=0;k<P;k++){
    const int j = t + k*T;
    float x=xyz[j*3+0], y=xyz[j*3+1], w=xyz[j*3+2];
    px[k]=x; py[k]=y; pz[k]=w; dist[k]=1e10f;
    sx[j]=x; sy[j]=y; szz[j]=w;
  }
  if (t==0){ s_acc[0]=0ull; s_acc[1]=0ull; s_acc[2]=0ull; }
  __syncthreads();
  unsigned long long win = (unsigned long long)(unsigned)(N-1);  // index 0
  for (int s=0;;s++){
    const int cur = (N-1) - (int)(unsigned)(win & 0xffffffffull);
    if (t==0){ nx[s*3+0]=sx[cur]; nx[s*3+1]=sy[cur]; nx[s*3+2]=szz[cur]; }
    if (s == NPOINT-1) break;
    const float cx=sx[cur], cy=sy[cur], cz=szz[cur];   // LDS broadcast
    // ---- scan: f32 only, paired (R9, measured best) ----
    float lm = -1.0f;
    #pragma unroll
    for (int k=0;k<P;k+=2){
      float dx0=px[k]-cx,   dy0=py[k]-cy,   dz0=pz[k]-cz;
      float dx1=px[k+1]-cx, dy1=py[k+1]-cy, dz1=pz[k+1]-cz;
      float d0 = fmaf(dz0,dz0, fmaf(dy0,dy0, dx0*dx0));   // XLA fma chain
      float d1 = fmaf(dz1,dz1, fmaf(dy1,dy1, dx1*dx1));
      float n0 = fminf(dist[k],   d0);
      float n1 = fminf(dist[k+1], d1);
      dist[k]=n0; dist[k+1]=n1;
      lm = fmaxf(lm, fmaxf(n0,n1));
    }
    // ---- local first-occurrence index (smallest k -> smallest j for this t) ----
    int kb = 0;
    #pragma unroll
    for (int k=P-1;k>=0;k--) if (dist[k]==lm) kb = k;
    // ---- phase 1: all-lanes max value ----
    const float wm = wave_fmax(lm);
    // ---- phase 2: min index among tied lanes ----
    int jc = (lm==wm) ? (t + kb*T) : 0x7fffffff;
    jc = wave_imin(jc);
    // ---- cross-wave: one packed-key LDS atomic per wave ----
    if ((t&63)==0)
      atomicMax(&s_acc[s%3], ((unsigned long long)__float_as_uint(wm)<<32)
                           | (unsigned long long)(unsigned)(N-1-jc));
    if (t==0) s_acc[(s+1)%3] = 0ull;   // reset next-next buffer (2 barriers from its reads)
    __syncthreads();
    win = s_acc[s%3];                  // broadcast read
  }
}

// ---------------- ball query: first K in-radius indices (ascending) + argmin fallback ----
template<int NSRC,int SQ,int K>
__global__ __launch_bounds__(64) void ball_query(const float* __restrict__ qxyz, const float* __restrict__ sxyz,
                                                 int* __restrict__ gidx, float r2)
{
  __shared__ float4 tile[1024];
  const int z = blockIdx.y, tid = threadIdx.x;
  const int s = blockIdx.x*64 + tid;
  const float* q = qxyz + (z*SQ+s)*3;
  const float qx=q[0],qy=q[1],qz=q[2];
  const float qq=nrm3(qx,qy,qz);
  int cnt=0, first=0, amin=0; float dmin=3.0e38f;
  int* out = gidx + (z*SQ+s)*K;
  for (int t0=0;t0<NSRC;t0+=1024){
    __syncthreads();
    for (int i=tid;i<1024;i+=64){
      const float* p = sxyz + (z*NSRC+t0+i)*3;
      float x=p[0],y=p[1],w=p[2];
      tile[i]=make_float4(x,y,w,nrm3(x,y,w));
    }
    __syncthreads();
    for (int jj=0;jj<1024;jj++){
      float4 p = tile[jj];
      float dot=dot3(qx,qy,qz,p.x,p.y,p.z);
      float d=(qq+p.w)-2.0f*dot;
      const int j = t0+jj;
      if (d < dmin){ dmin=d; amin=j; }
      if (d <= r2 && cnt < K){ if(cnt==0) first=j; out[cnt]=j; cnt++; }
    }
  }
  const int fill = (cnt==0)? amin : first;
  for (int c=cnt;c<K;c++) out[c]=fill;
}

// ---------------- set-abstraction conv passes ----------------
template<int S,int K,int CF,int C1,int C2,int NSRC,int PASS>
__global__ __launch_bounds__(256) void sa_pass(
    const float* __restrict__ srcxyz, const float* __restrict__ srcfea,
    const float* __restrict__ qxyz, const int* __restrict__ gidx,
    const float* __restrict__ w0, const float* __restrict__ g0, const float* __restrict__ b0,
    const float* __restrict__ w1, const float* __restrict__ g1v, const float* __restrict__ b1v,
    float* __restrict__ stats, int offA, int offB, float cnt0, float cnt1,
    float* __restrict__ outp)
{
  constexpr int CIN = 3+CF;
  __shared__ float w0l[C1*CIN];
  __shared__ float w1l[PASS>=2 ? C2*C1 : 1];
  __shared__ float sc0[C1], bi0[C1];
  __shared__ float sc1[C2], bi1[C2];
  __shared__ float sred[4][128];
  const int z = blockIdx.y, pipe = z>>1, tid = threadIdx.x;
  float* stA = stats + pipe*1024 + offA;
  float* stB = stats + pipe*1024 + offB;
  for (int i=tid;i<C1*CIN;i+=256) w0l[i]=w0[i];
  if (PASS>=2){
    for (int i=tid;i<C2*C1;i+=256) w1l[i]=w1[i];
    if (tid<C1){
      float m = stA[tid]/cnt0;
      float var = stA[C1+tid]/cnt0 - m*m;
      float rs = 1.0f/sqrtf(var+1e-5f);
      float sc = rs*g0[tid];
      sc0[tid]=sc; bi0[tid]=b0[tid]-m*sc;
    }
  }
  if (PASS==3 && tid<C2){
    float m = stB[tid]/cnt1;
    float var = stB[C2+tid]/cnt1 - m*m;
    float rs = 1.0f/sqrtf(var+1e-5f);
    float sc = rs*g1v[tid];
    sc1[tid]=sc; bi1[tid]=b1v[tid]-m*sc;
  }
  __syncthreads();
  const int item = blockIdx.x*256+tid;
  const int s = item/K;
  const int j = gidx[(z*S+s)*K + (item%K)];
  const float* q = qxyz + (z*S+s)*3;
  const float* p = srcxyz + (z*NSRC+j)*3;
  float f[CIN];
  f[0]=p[0]-q[0]; f[1]=p[1]-q[1]; f[2]=p[2]-q[2];
  const float* fe = srcfea + (z*NSRC+j)*CF;
  #pragma unroll
  for (int c=0;c<CF;c++) f[3+c]=fe[c];
  float h1[C1];
  #pragma unroll
  for (int o=0;o<C1;o++){
    float a=0.f;
    #pragma unroll
    for (int c=0;c<CIN;c++) a = fmaf(w0l[o*CIN+c], f[c], a);
    h1[o]=a;
  }
  if (PASS==1){ stats_accum<C1>(h1, stA, sred); return; }
  float f2v[C1];
  #pragma unroll
  for (int o=0;o<C1;o++) f2v[o]=fmaxf(fmaf(h1[o],sc0[o],bi0[o]), 0.f);
  float h2[C2];
  #pragma unroll
  for (int o=0;o<C2;o++){
    float a=0.f;
    #pragma unroll
    for (int c=0;c<C1;c++) a = fmaf(w1l[o*C1+c], f2v[c], a);
    h2[o]=a;
  }
  if (PASS==2){ stats_accum<C2>(h2, stB, sred); return; }
  #pragma unroll
  for (int o=0;o<C2;o++) h2[o]=fmaxf(fmaf(h2[o],sc1[o],bi1[o]), 0.f);
  #pragma unroll
  for (int msk=1; msk<K; msk<<=1){
    #pragma unroll
    for (int o=0;o<C2;o++) h2[o]=fmaxf(h2[o], __shfl_xor(h2[o], msk, 64));
  }
  if ((tid & (K-1))==0){
    float* op = outp + (z*S+s)*C2;
    #pragma unroll
    for (int o=0;o<C2;o++) op[o]=h2[o];
  }
}

// ---------------- upconv: stable 8-NN (64-thread blocks, order-preserving) ----------------
__global__ __launch_bounds__(64) void up_top8(const float* __restrict__ nx1, const float* __restrict__ nx2,
                                              int* __restrict__ uidx)
{
  __shared__ float4 tile[1024];
  const int z=blockIdx.y, tid=threadIdx.x;
  const int s=blockIdx.x*64+tid;
  const float* q = nx1 + (z*4096+s)*3;
  const float qx=q[0],qy=q[1],qz=q[2];
  const float qq=nrm3(qx,qy,qz);
  for (int i=tid;i<1024;i+=64){
    const float* p = nx2 + (z*1024+i)*3;
    float x=p[0],y=p[1],w=p[2];
    tile[i]=make_float4(x,y,w,nrm3(x,y,w));
  }
  __syncthreads();
  float d[8]; int id[8];
  #pragma unroll
  for (int r=0;r<8;r++){ d[r]=3e38f; id[r]=0; }
  for (int j=0;j<1024;j++){
    float4 p=tile[j];
    float dt=dot3(qx,qy,qz,p.x,p.y,p.z);
    float dd=(qq+p.w)-2.0f*dt;
    if (dd<d[7]){
      d[7]=dd; id[7]=j;
      #pragma unroll
      for (int r=7;r>0;r--){
        if (d[r]<d[r-1]){ float td=d[r-1]; d[r-1]=d[r]; d[r]=td; int ti=id[r-1]; id[r-1]=id[r]; id[r]=ti; }
      }
    }
  }
  int* o = uidx + (z*4096+s)*8;
  #pragma unroll
  for (int r=0;r<8;r++) o[r]=id[r];
}

template<int PASS>
__global__ __launch_bounds__(256) void up_pass(
    const float* __restrict__ nx1, const float* __restrict__ nx2,
    const float* __restrict__ l2f, const float* __restrict__ l1f,
    const int* __restrict__ uidx,
    const float* __restrict__ w1, const float* __restrict__ g1v, const float* __restrict__ b1v,
    const float* __restrict__ w2,
    float* __restrict__ stats, float* __restrict__ uh2)
{
  __shared__ float w1l[32*67];
  __shared__ float w2l[PASS==2?32*64:1];
  __shared__ float sc0[32], bi0[32];
  __shared__ float sred[4][128];
  const int z=blockIdx.y, pipe=z>>1, tid=threadIdx.x;
  float* stU1 = stats + pipe*1024 + ST_U1;
  float* stU2 = stats + pipe*1024 + ST_U2;
  for (int i=tid;i<32*67;i+=256) w1l[i]=w1[i];
  if (PASS==2){
    for (int i=tid;i<32*64;i+=256) w2l[i]=w2[i];
    if (tid<32){
      float m=stU1[tid]/65536.f;
      float var=stU1[32+tid]/65536.f - m*m;
      float rs=1.0f/sqrtf(var+1e-5f);
      float sc=rs*g1v[tid];
      sc0[tid]=sc; bi0[tid]=b1v[tid]-m*sc;
    }
  }
  __syncthreads();
  const int item = blockIdx.x*256+tid;
  const int s = item>>3, k = item&7;
  const int j = uidx[(z*4096+s)*8+k];
  float f67[67];
  const float* fe = l2f + (z*1024+j)*64;
  #pragma unroll
  for (int c=0;c<64;c++) f67[c]=fe[c];
  const float* pp = nx2 + (z*1024+j)*3;
  const float* qv = nx1 + (z*4096+s)*3;
  f67[64]=pp[0]-qv[0]; f67[65]=pp[1]-qv[1]; f67[66]=pp[2]-qv[2];
  float h[32];
  #pragma unroll
  for (int o=0;o<32;o++){
    float a=0.f;
    #pragma unroll
    for (int c=0;c<67;c++) a=fmaf(w1l[o*67+c], f67[c], a);
    h[o]=a;
  }
  if (PASS==1){ stats_accum<32>(h, stU1, sred); return; }
  #pragma unroll
  for (int o=0;o<32;o++) h[o]=fmaxf(fmaf(h[o],sc0[o],bi0[o]),0.f);
  #pragma unroll
  for (int msk=1; msk<8; msk<<=1){
    #pragma unroll
    for (int o=0;o<32;o++) h[o]=fmaxf(h[o], __shfl_xor(h[o],msk,64));
  }
  float h2[32];
  if (k==0){
    const float* l1 = l1f + (z*4096+s)*32;
    #pragma unroll
    for (int o=0;o<32;o++){
      float a=0.f;
      #pragma unroll
      for (int c=0;c<32;c++) a=fmaf(w2l[o*64+c], h[c], a);
      #pragma unroll
      for (int c=0;c<32;c++) a=fmaf(w2l[o*64+32+c], l1[c], a);
      h2[o]=a;
    }
    float* up = uh2 + (z*4096+s)*32;
    #pragma unroll
    for (int o=0;o<32;o++) up[o]=h2[o];
  } else {
    #pragma unroll
    for (int o=0;o<32;o++) h2[o]=0.f;
  }
  stats_accum<32>(h2, stU2, sred);
}

__global__ __launch_bounds__(256) void up_norm(const float* __restrict__ uh2, const float* __restrict__ g,
                                               const float* __restrict__ b, const float* __restrict__ stats,
                                               float* __restrict__ l1n)
{
  const int i = blockIdx.x*256+threadIdx.x;   // < 4*4096*32
  const int z = i>>17, pipe = z>>1, c = i&31;
  const float* st = stats + pipe*1024 + ST_U2;
  float m = st[c]/8192.f;
  float var = st[32+c]/8192.f - m*m;
  float rs = 1.0f/sqrtf(var+1e-5f);
  float sc = rs*g[c];
  float bi = b[c]-m*sc;
  l1n[i]=fmaxf(fmaf(uh2[i],sc,bi),0.f);
}

// ---------------- feature propagation: 3-NN interpolate + conv ----------------
__global__ __launch_bounds__(256) void fp_kern(
  const float* __restrict__ xyzf, const float* __restrict__ feaf,
  const float* __restrict__ nx1, const float* __restrict__ l1n,
  const float* __restrict__ fpw, float* __restrict__ stats, float* __restrict__ h3)
{
  __shared__ float4 tile[2048];
  __shared__ float wl[32*42];
  __shared__ float sred[4][128];
  const int z=blockIdx.y, pipe=z>>1, tid=threadIdx.x;
  for (int i=tid;i<32*42;i+=256) wl[i]=fpw[i];
  const int n = blockIdx.x*256+tid;
  const float* q = xyzf + (z*8192+n)*3;
  const float qx=q[0],qy=q[1],qz=q[2];
  const float qq2=nrm3(qx,qy,qz);
  float d0=3e38f,d1=3e38f,d2=3e38f; int i0=0,i1=0,i2=0;
  for (int t0=0;t0<4096;t0+=2048){
    __syncthreads();
    for (int i=tid;i<2048;i+=256){
      const float* p = nx1 + (z*4096+t0+i)*3;
      float x=p[0],y=p[1],w=p[2];
      tile[i]=make_float4(x,y,w,nrm3(x,y,w));
    }
    __syncthreads();
    for (int jj=0;jj<2048;jj++){
      float4 p=tile[jj];
      float dt=dot3(qx,qy,qz,p.x,p.y,p.z);
      float d=(qq2+p.w)-2.0f*dt;
      if (d<d2){
        d2=d; i2=t0+jj;
        if (d2<d1){ float td=d1; d1=d2; d2=td; int ti=i1; i1=i2; i2=ti; }
        if (d1<d0){ float td=d0; d0=d1; d1=td; int ti=i0; i0=i1; i1=ti; }
      }
    }
  }
  d0=fmaxf(d0,1e-10f); d1=fmaxf(d1,1e-10f); d2=fmaxf(d2,1e-10f);
  float w0=1.0f/d0, w1=1.0f/d1, w2=1.0f/d2;
  float wsum=(w0+w1)+w2;
  w0/=wsum; w1/=wsum; w2/=wsum;
  const float* A = l1n + (z*4096+i0)*32;
  const float* B = l1n + (z*4096+i1)*32;
  const float* C = l1n + (z*4096+i2)*32;
  float f[42];
  #pragma unroll
  for (int c=0;c<32;c++) f[c]=fmaf(C[c],w2, fmaf(B[c],w1, A[c]*w0));
  const float* fe = feaf + (z*8192+n)*10;
  #pragma unroll
  for (int c=0;c<10;c++) f[32+c]=fe[c];
  float h[32];
  #pragma unroll
  for (int o=0;o<32;o++){
    float a=0.f;
    #pragma unroll
    for (int c=0;c<42;c++) a=fmaf(wl[o*42+c], f[c], a);
    h[o]=a;
    h3[(z*8192+n)*32+o]=a;
  }
  stats_accum<32>(h, stats + pipe*1024 + ST_FP, sred);
}

__global__ __launch_bounds__(256) void fp_post(const float* __restrict__ h3, const float* __restrict__ g,
                                               const float* __restrict__ b, float* __restrict__ stats,
                                               float* __restrict__ l0n)
{
  __shared__ float sc[32], bi[32];
  __shared__ float sred[4][128];
  const int tid=threadIdx.x;
  const int row = blockIdx.x*256+tid;     // 32768
  const int pipe = row>>14;
  float* stF = stats + pipe*1024 + ST_FP;
  float* stB = stats + pipe*1024 + ST_BN1;
  if (tid<32){
    float m=stF[tid]/16384.f;
    float var=stF[32+tid]/16384.f-m*m;
    float rs=1.0f/sqrtf(var+1e-5f);
    float s=rs*g[tid];
    sc[tid]=s; bi[tid]=b[tid]-m*s;
  }
  __syncthreads();
  float x[32];
  #pragma unroll
  for (int c=0;c<32;c++){ x[c]=fmaxf(fmaf(h3[row*32+c],sc[c],bi[c]),0.f); l0n[row*32+c]=x[c]; }
  stats_accum<32>(x, stB, sred);
}

__global__ __launch_bounds__(256) void final_kern(
  const float* __restrict__ l0n, const float* __restrict__ g, const float* __restrict__ b,
  const float* __restrict__ cw, const float* __restrict__ cb,
  const float* __restrict__ p1, const float* __restrict__ p2,
  const float* __restrict__ stats, float* __restrict__ out)
{
  __shared__ float sc[32], bi[32], wl[512], bl[16];
  const int tid=threadIdx.x;
  const int row = blockIdx.x*256+tid;
  const int z=row>>13, pipe=z>>1, bb=z&1, n=row&8191;
  const float* st = stats + pipe*1024 + ST_BN1;
  if (tid<32){
    float m=st[tid]/16384.f;
    float var=st[32+tid]/16384.f-m*m;
    float rs=1.0f/sqrtf(var+1e-5f);
    float s=rs*g[tid];
    sc[tid]=s; bi[tid]=b[tid]-m*s;
  }
  for (int i=tid;i<512;i+=256) wl[i]=cw[i];
  if (tid<16) bl[tid]=cb[tid];
  __syncthreads();
  float x[32];
  #pragma unroll
  for (int c=0;c<32;c++) x[c]=fmaxf(fmaf(l0n[row*32+c],sc[c],bi[c]),0.f);
  float* o = out + row*19;
  const float* ps = (pipe?p2:p1) + (bb*8192+n)*3;
  o[0]=ps[0]; o[1]=ps[1]; o[2]=ps[2];
  #pragma unroll
  for (int oo=0;oo<16;oo++){
    float a=0.f;
    #pragma unroll
    for (int c=0;c<32;c++) a=fmaf(wl[oo*32+c],x[c],a);
    o[3+oo]=a+bl[oo];
  }
}

// ---------------- host ----------------
extern "C" void kernel_launch(void* const* d_in, const int* in_sizes, int n_in,
                              void* d_out, int out_size, void* d_ws, size_t ws_size,
                              hipStream_t stream)
{
  (void)in_sizes; (void)n_in; (void)out_size; (void)ws_size;
  const float* p1 = (const float*)d_in[0];
  const float* f1 = (const float*)d_in[1];
  const float* p2 = (const float*)d_in[2];
  const float* f2 = (const float*)d_in[3];
  const float *sa1_w0=(const float*)d_in[4], *sa1_g0=(const float*)d_in[5], *sa1_b0=(const float*)d_in[6];
  const float *sa1_w1=(const float*)d_in[7], *sa1_g1=(const float*)d_in[8], *sa1_b1=(const float*)d_in[9];
  const float *sa2_w0=(const float*)d_in[10],*sa2_g0=(const float*)d_in[11],*sa2_b0=(const float*)d_in[12];
  const float *sa2_w1=(const float*)d_in[13],*sa2_g1=(const float*)d_in[14],*sa2_b1=(const float*)d_in[15];
  const float *su1_w1=(const float*)d_in[16],*su1_g1=(const float*)d_in[17],*su1_b1=(const float*)d_in[18];
  const float *su1_w2=(const float*)d_in[19],*su1_g2=(const float*)d_in[20],*su1_b2=(const float*)d_in[21];
  const float *fp_w=(const float*)d_in[22], *fp_g=(const float*)d_in[23], *fp_b=(const float*)d_in[24];
  const float *bn1_g=(const float*)d_in[25],*bn1_b=(const float*)d_in[26];
  const float *conv2_w=(const float*)d_in[27],*conv2_b=(const float*)d_in[28];
  float* wsf=(float*)d_ws; int* wsi=(int*)d_ws;
  float* xyzf=wsf+OFF_XYZF; float* feaf=wsf+OFF_FEAF;
  float* nx1=wsf+OFF_NX1; float* l1f=wsf+OFF_L1F;
  float* nx2=wsf+OFF_NX2; float* l2f=wsf+OFF_L2F;
  float* uh2=wsf+OFF_UH2; float* l1n=wsf+OFF_L1N;
  float* h3=wsf+OFF_H3; float* l0n=wsf+OFF_L0N;
  float* stats=wsf+OFF_STATS;
  int* gidx1=wsi+OFF_GIDX1; int* gidx2=wsi+OFF_GIDX2; int* uidx=wsi+OFF_UIDX;
  // radius*radius is computed in Python f64 then demoted to f32
  const float R2A=(float)(0.1*0.1), R2B=(float)(0.2*0.2);

  (void)hipMemsetAsync(stats, 0, 2048*sizeof(float), stream);
  prep<<<128,256,0,stream>>>(p1,f1,p2,f2,xyzf,feaf);
  fps_kernel<8192,4096,512><<<4,512,0,stream>>>(xyzf, nx1);
  ball_query<8192,4096,16><<<dim3(64,4),64,0,stream>>>(nx1, xyzf, gidx1, R2A);
  sa_pass<4096,16,10,16,32,8192,1><<<dim3(256,4),256,0,stream>>>(xyzf,feaf,nx1,gidx1,
      sa1_w0,sa1_g0,sa1_b0,sa1_w1,sa1_g1,sa1_b1, stats,ST_SA1A,ST_SA1B,131072.f,131072.f, l1f);
  sa_pass<4096,16,10,16,32,8192,2><<<dim3(256,4),256,0,stream>>>(xyzf,feaf,nx1,gidx1,
      sa1_w0,sa1_g0,sa1_b0,sa1_w1,sa1_g1,sa1_b1, stats,ST_SA1A,ST_SA1B,131072.f,131072.f, l1f);
  sa_pass<4096,16,10,16,32,8192,3><<<dim3(256,4),256,0,stream>>>(xyzf,feaf,nx1,gidx1,
      sa1_w0,sa1_g0,sa1_b0,sa1_w1,sa1_g1,sa1_b1, stats,ST_SA1A,ST_SA1B,131072.f,131072.f, l1f);
  fps_kernel<4096,1024,512><<<4,512,0,stream>>>(nx1, nx2);
  ball_query<4096,1024,16><<<dim3(16,4),64,0,stream>>>(nx2, nx1, gidx2, R2B);
  sa_pass<1024,16,32,32,64,4096,1><<<dim3(64,4),256,0,stream>>>(nx1,l1f,nx2,gidx2,
      sa2_w0,sa2_g0,sa2_b0,sa2_w1,sa2_g1,sa2_b1, stats,ST_SA2A,ST_SA2B,32768.f,32768.f, l2f);
  sa_pass<1024,16,32,32,64,4096,2><<<dim3(64,4),256,0,stream>>>(nx1,l1f,nx2,gidx2,
      sa2_w0,sa2_g0,sa2_b0,sa2_w1,sa2_g1,sa2_b1, stats,ST_SA2A,ST_SA2B,32768.f,32768.f, l2f);
  sa_pass<1024,16,32,32,64,4096,3><<<dim3(64,4),256,0,stream>>>(nx1,l1f,nx2,gidx2,
      sa2_w0,sa2_g0,sa2_b0,sa2_w1,sa2_g1,sa2_b1, stats,ST_SA2A,ST_SA2B,32768.f,32768.f, l2f);
  up_top8<<<dim3(64,4),64,0,stream>>>(nx1,nx2,uidx);
  up_pass<1><<<dim3(128,4),256,0,stream>>>(nx1,nx2,l2f,l1f,uidx,su1_w1,su1_g1,su1_b1,su1_w2,stats,uh2);
  up_pass<2><<<dim3(128,4),256,0,stream>>>(nx1,nx2,l2f,l1f,uidx,su1_w1,su1_g1,su1_b1,su1_w2,stats,uh2);
  up_norm<<<2048,256,0,stream>>>(uh2,su1_g2,su1_b2,stats,l1n);
  fp_kern<<<dim3(32,4),256,0,stream>>>(xyzf,feaf,nx1,l1n,fp_w,stats,h3);
  fp_post<<<128,256,0,stream>>>(h3,fp_g,fp_b,stats,l0n);
  final_kern<<<128,256,0,stream>>>(l0n,bn1_g,bn1_b,conv2_w,conv2_b,p1,p2,stats,(float*)d_out);
}